// Round 1
// baseline (2936.529 us; speedup 1.0000x reference)
//
#include <hip/hip_runtime.h>
#include <hip/hip_bf16.h>

// B=2048, D=256, H=266 (pad N->272, K->288), S=50. All f32 I/O; bf16 MFMA inside.
// PERSISTENT-KERNEL VERSION: the former k_init / v0 chain / k_lin / k_fused
// per-step launches (~106 serial dispatches, ~10-15us boundary cost each) are
// collapsed into ONE kernel (grid 256x256, 1 block/CU, co-resident by capacity)
// with a manual two-level agent-scope grid barrier. Phase bodies and global
// dataflow are identical to the verified multi-kernel version. Weights are
// pre-swizzled to MFMA B-fragment layout by k_conv (unchanged).

#define BATCH 2048
#define DD    256
#define HH    266
#define HP    272
#define SS    50
#define BN_EPS 1e-5f
#define SIG   0.3f
#define AS_STRIDE 296   // LDS A-tile row stride in bf16 elements (16B-aligned, bank-spread)

// f32 workspace offsets
#define XC_OFF 0              // [2048][256]
#define Y1_OFF 524288         // [2048][272]
#define Y2_OFF 1081344        // [2048][272]
#define V_OFF  1638400        // [2048]
#define S1_OFF 1640448        // 2 parity x 8 reps x 544
#define S2_OFF 1649152
#define S1V_OFF 1657856       // 8 x 544
#define S2V_OFF 1662208
#define SV_OFF  1666560       // 16
#define WQ_OFF  1666576       // bf16 region starts here (x4 bytes, 16B aligned)

// swizzled weight strides (ushort units)
#define W1S 69632   // 8kt*17nt*512
#define W2S 78336   // 9*17*512
#define W3S 73728   // 9*16*512
#define W1Q_OFF 0
#define W2Q_OFF 3481600
#define W3Q_OFF 7398400
#define WV1Q_OFF 11084800
#define WV2Q_OFF 11154432

// barrier state: u32[512] at f32 index BAR_OFF (past end of WQ region, ~29.1MB total)
#define BAR_OFF 7283200

typedef unsigned short ushort_t;
using short8 = __attribute__((ext_vector_type(8))) short;
using f32x4  = __attribute__((ext_vector_type(4))) float;

__device__ __forceinline__ ushort_t f2b(float f) {   // f32 -> bf16 bits, RNE
    unsigned u = __float_as_uint(f);
    unsigned r = u + 0x7FFF + ((u >> 16) & 1);
    return (ushort_t)(r >> 16);
}

// ---------------- weight swizzle: f32 [K][N] -> bf16 B-frag layout ----------------
__global__ __launch_bounds__(256) void k_conv(const float* __restrict__ src,
                                              ushort_t* __restrict__ dst,
                                              int K, int N, int KT, int NT,
                                              long total) {
    long t = (long)blockIdx.x * 256 + threadIdx.x;
    if (t >= total) return;
    int per = KT * NT * 512;
    int step = (int)(t / per);
    int e = (int)(t - (long)step * per);
    int kt = e / (NT * 512);
    int r = e - kt * NT * 512;
    int nt = r / 512;
    int r2 = r & 511;
    int lane = r2 >> 3;
    int j = r2 & 7;
    int k = kt * 32 + (lane >> 4) * 8 + j;
    int n = nt * 16 + (lane & 15);
    float v = (k < K && n < N) ? src[(size_t)step * K * N + (size_t)k * N + n] : 0.f;
    dst[t] = f2b(v);
}

// ---------------- barrier pre-init (ws is poisoned between bench iterations) ----
__global__ __launch_bounds__(256) void k_pre(float* __restrict__ ws) {
    unsigned* bar = (unsigned*)(ws + BAR_OFF);
    for (int i = threadIdx.x; i < 512; i += 256) bar[i] = 0u;
}

// ---------------- two-level grid barrier (agent scope, cross-XCD safe) ----------
// leaf[bid&7] (128B apart) -> root -> rel. Release fence (L2 writeback) before
// arrival, acquire fence (L1/L2 invalidate) after release observed — same cache
// maintenance a kernel boundary performs, so plain-load/store dataflow between
// phases keeps the exact semantics of the multi-kernel version.
__device__ __forceinline__ void grid_bar(unsigned* bar, unsigned gen, int bid) {
    __syncthreads();                       // all waves' stores issued & drained
    if (threadIdx.x == 0) {
        __builtin_amdgcn_fence(__ATOMIC_RELEASE, "agent");   // wb L2 -> LLC
        unsigned* leaf = bar + (bid & 7) * 32;
        unsigned* root = bar + 256;
        unsigned* rel  = bar + 288;
        unsigned a = __hip_atomic_fetch_add(leaf, 1u, __ATOMIC_RELAXED, __HIP_MEMORY_SCOPE_AGENT);
        if (a == 31) {
            __hip_atomic_store(leaf, 0u, __ATOMIC_RELAXED, __HIP_MEMORY_SCOPE_AGENT);
            unsigned r = __hip_atomic_fetch_add(root, 1u, __ATOMIC_RELAXED, __HIP_MEMORY_SCOPE_AGENT);
            if (r == 7) {
                __hip_atomic_store(root, 0u, __ATOMIC_RELAXED, __HIP_MEMORY_SCOPE_AGENT);
                __hip_atomic_fetch_add(rel, 1u, __ATOMIC_RELEASE, __HIP_MEMORY_SCOPE_AGENT);
            } else {
                while (__hip_atomic_load(rel, __ATOMIC_RELAXED, __HIP_MEMORY_SCOPE_AGENT) == gen)
                    __builtin_amdgcn_s_sleep(2);
            }
        } else {
            while (__hip_atomic_load(rel, __ATOMIC_RELAXED, __HIP_MEMORY_SCOPE_AGENT) == gen)
                __builtin_amdgcn_s_sleep(2);
        }
        __builtin_amdgcn_fence(__ATOMIC_ACQUIRE, "agent");   // inv L1+L2
    }
    __syncthreads();
}

// BN affine constants: A = relu(a*y + c)
__device__ __forceinline__ void compute_ac(const float* __restrict__ stats_in,
                                           const float* __restrict__ g,
                                           const float* __restrict__ be,
                                           float (*AC)[HP]) {
    for (int t = threadIdx.x; t < HP; t += 256) {
        float a = 0.f, c = 0.f;
        if (t < HH) {
            float s = 0.f, q = 0.f;
            #pragma unroll
            for (int r = 0; r < 8; ++r) {
                s += stats_in[r * 544 + t];
                q += stats_in[r * 544 + 272 + t];
            }
            float mu  = s * (1.0f / 2048.0f);
            float var = q * (1.0f / 2048.0f) - mu * mu;
            float rs  = rsqrtf(fmaxf(var, 0.0f) + BN_EPS);
            a = g[t] * rs;
            c = be[t] - mu * a;
        }
        AC[0][t] = a;
        AC[1][t] = c;
    }
}

// ---------------- phase: [affine-relu] GEMM (NT=17) + stats ----------------
// mode 0: raw f32 xsrc (K=KT*32); mode 2: affine(stats) on Y. 256 blocks (128 M x 2 N-halves).
__device__ __forceinline__ void dev_lin(
    int bid, int mode, int KT, const float* __restrict__ xsrc, int xld,
    const float* __restrict__ stats_in, const float* __restrict__ g,
    const float* __restrict__ be,
    const ushort_t* __restrict__ Wq, const float* __restrict__ bias,
    float* __restrict__ yout, float* __restrict__ stats_out,
    float* __restrict__ zero_ptr,
    ushort_t* __restrict__ As, float (*AC)[HP])
{
    const int tid  = threadIdx.x;
    const int lane = tid & 63;
    const int wv   = tid >> 6;
    const int quad = lane >> 4;
    const int l15  = lane & 15;
    const int h    = bid & 1;
    const int row0 = (bid >> 1) * 16;

    if (zero_ptr != nullptr && bid < 17)
        zero_ptr[bid * 256 + tid] = 0.0f;

    if (mode == 2) { compute_ac(stats_in, g, be, AC); __syncthreads(); }

    const int PAIRS = KT * 16;
    for (int idx = tid; idx < 16 * PAIRS; idx += 256) {
        int m  = idx / PAIRS;
        int kk = (idx - m * PAIRS) * 2;
        float v0, v1;
        if (mode == 2) {
            v0 = (kk < HH)     ? fmaxf(fmaf(AC[0][kk],     xsrc[(size_t)(row0+m)*xld + kk],     AC[1][kk]),     0.f) : 0.f;
            v1 = (kk+1 < HH)   ? fmaxf(fmaf(AC[0][kk+1],   xsrc[(size_t)(row0+m)*xld + kk+1],   AC[1][kk+1]),   0.f) : 0.f;
        } else {
            v0 = xsrc[(size_t)(row0+m)*xld + kk];
            v1 = xsrc[(size_t)(row0+m)*xld + kk + 1];
        }
        ((unsigned int*)As)[m * (AS_STRIDE/2) + (kk >> 1)] =
            (unsigned int)f2b(v0) | ((unsigned int)f2b(v1) << 16);
    }
    __syncthreads();

    const int tbase = h ? 9 : 0;
    const int tlim  = h ? 17 : 9;
    f32x4 acc[3];
    #pragma unroll
    for (int i = 0; i < 3; ++i) acc[i] = (f32x4){0.f, 0.f, 0.f, 0.f};

    for (int kt = 0; kt < KT; ++kt) {
        short8 af = *(const short8*)(&As[l15 * AS_STRIDE + kt * 32 + quad * 8]);
        const ushort_t* wp = Wq + ((size_t)(kt * 17 + tbase + wv)) * 512 + lane * 8;
        #pragma unroll
        for (int i = 0; i < 3; ++i) {
            int t = tbase + wv + i * 4;
            if (t < tlim) {
                short8 bf = *(const short8*)(wp + (size_t)i * 4 * 512);
                acc[i] = __builtin_amdgcn_mfma_f32_16x16x32_bf16(af, bf, acc[i], 0, 0, 0);
            }
        }
    }

    #pragma unroll
    for (int i = 0; i < 3; ++i) {
        int t = tbase + wv + i * 4;
        if (t >= tlim) continue;
        int col = t * 16 + l15;
        float bj = (col < HH) ? bias[col] : 0.f;
        float y0 = acc[i][0] + bj, y1 = acc[i][1] + bj;
        float y2 = acc[i][2] + bj, y3 = acc[i][3] + bj;
        yout[(size_t)(row0 + quad*4 + 0) * HP + col] = y0;
        yout[(size_t)(row0 + quad*4 + 1) * HP + col] = y1;
        yout[(size_t)(row0 + quad*4 + 2) * HP + col] = y2;
        yout[(size_t)(row0 + quad*4 + 3) * HP + col] = y3;
        float sp = y0 + y1 + y2 + y3;
        float sq = y0*y0 + y1*y1 + y2*y2 + y3*y3;
        sp += __shfl_xor(sp, 16); sp += __shfl_xor(sp, 32);
        sq += __shfl_xor(sq, 16); sq += __shfl_xor(sq, 32);
        if (quad == 0 && col < HH) {
            float* spp = stats_out + (bid & 7) * 544;
            atomicAdd(spp + col, sp);
            atomicAdd(spp + 272 + col, sq);
        }
    }
}

// ---------------- phase: P3 grad GEMM + v/xc update + P1(s+1) GEMM ----------------
// 128 blocks (16 rows/block, full N per block for row reductions).
__device__ __forceinline__ void dev_fused(
    int bid,
    const float* __restrict__ y2g, const float* __restrict__ stats_in,
    const float* __restrict__ g2, const float* __restrict__ be2,
    const ushort_t* __restrict__ W3q, const float* __restrict__ b3,
    const float* __restrict__ law, const float* __restrict__ dWs,
    const float* __restrict__ tg, int s, int doP1,
    float* __restrict__ xc, float* __restrict__ vv, float* __restrict__ outv,
    const ushort_t* __restrict__ W1q, const float* __restrict__ b1n,
    float* __restrict__ Y1, float* __restrict__ stats_out,
    float* __restrict__ zero_ptr,
    ushort_t* __restrict__ As, float (*AC)[HP], float* __restrict__ red)
{
    const int tid  = threadIdx.x;
    const int lane = tid & 63;
    const int wv   = tid >> 6;
    const int quad = lane >> 4;
    const int l15  = lane & 15;
    const int row0 = bid * 16;
    #define RED(w,q,r,j) red[((((w)*4+(q))*4+(r))*3)+(j)]

    if (zero_ptr != nullptr && bid < 17)
        zero_ptr[bid * 256 + tid] = 0.0f;

    compute_ac(stats_in, g2, be2, AC);
    __syncthreads();

    // stage A2 = relu(affine(Y2)) into LDS, K padded to 288
    for (int idx = tid; idx < 16 * 144; idx += 256) {
        int m  = idx / 144;
        int kk = (idx - m * 144) * 2;
        float v0 = (kk < HH)   ? fmaxf(fmaf(AC[0][kk],   y2g[(size_t)(row0+m)*HP + kk],   AC[1][kk]),   0.f) : 0.f;
        float v1 = (kk+1 < HH) ? fmaxf(fmaf(AC[0][kk+1], y2g[(size_t)(row0+m)*HP + kk+1], AC[1][kk+1]), 0.f) : 0.f;
        ((unsigned int*)As)[m * (AS_STRIDE/2) + (kk >> 1)] =
            (unsigned int)f2b(v0) | ((unsigned int)f2b(v1) << 16);
    }
    __syncthreads();

    // P3 GEMM: KT=9, NT=16, wave wv owns tiles wv+4i
    f32x4 acc[4];
    #pragma unroll
    for (int i = 0; i < 4; ++i) acc[i] = (f32x4){0.f, 0.f, 0.f, 0.f};
    for (int kt = 0; kt < 9; ++kt) {
        short8 af = *(const short8*)(&As[l15 * AS_STRIDE + kt * 32 + quad * 8]);
        const ushort_t* wp = W3q + ((size_t)(kt * 16 + wv)) * 512 + lane * 8;
        #pragma unroll
        for (int i = 0; i < 4; ++i) {
            short8 bf = *(const short8*)(wp + (size_t)i * 4 * 512);
            acc[i] = __builtin_amdgcn_mfma_f32_16x16x32_bf16(af, bf, acc[i], 0, 0, 0);
        }
    }

    // epilogue: grad, row partials
    const float h   = tg[s + 1] - tg[s];
    const float srt = SIG * sqrtf(h);
    float grad[4][4], xcv[4][4], dwv[4][4];
    float sxr[4] = {0,0,0,0}, sgr[4] = {0,0,0,0}, sgnr[4] = {0,0,0,0};
    #pragma unroll
    for (int i = 0; i < 4; ++i) {
        int col = (wv + 4*i) * 16 + l15;
        #pragma unroll
        for (int r = 0; r < 4; ++r) {
            int row = row0 + quad * 4 + r;
            float gd = acc[i][r] + b3[col];
            float xv = xc[(size_t)row * DD + col];
            float dw = dWs[(size_t)row * DD + col];
            float d  = xv - law[col];
            grad[i][r] = gd; xcv[i][r] = xv; dwv[i][r] = dw;
            sxr[r]  = fmaf(d, d, sxr[r]);
            sgr[r]  = fmaf(gd, gd, sgr[r]);
            sgnr[r] = fmaf(gd, dw, sgnr[r]);
        }
    }
    #pragma unroll
    for (int off = 1; off < 16; off <<= 1) {
        #pragma unroll
        for (int r = 0; r < 4; ++r) {
            sxr[r]  += __shfl_xor(sxr[r],  off);
            sgr[r]  += __shfl_xor(sgr[r],  off);
            sgnr[r] += __shfl_xor(sgnr[r], off);
        }
    }
    if (l15 == 0) {
        #pragma unroll
        for (int r = 0; r < 4; ++r) {
            RED(wv, quad, r, 0) = sxr[r];
            RED(wv, quad, r, 1) = sgr[r];
            RED(wv, quad, r, 2) = sgnr[r];
        }
    }
    __syncthreads();   // red ready; also all waves done reading As

    if (wv == 0 && l15 == 0) {
        #pragma unroll
        for (int r = 0; r < 4; ++r) {
            int row = row0 + quad * 4 + r;
            float sx  = RED(0,quad,r,0) + RED(1,quad,r,0) + RED(2,quad,r,0) + RED(3,quad,r,0);
            float sg  = RED(0,quad,r,1) + RED(1,quad,r,1) + RED(2,quad,r,1) + RED(3,quad,r,1);
            float sgn = RED(0,quad,r,2) + RED(1,quad,r,2) + RED(2,quad,r,2) + RED(3,quad,r,2);
            float f  = 0.5f * (sx + sg);
            float vn = vv[row] - f * h + srt * sgn;
            vv[row] = vn;
            if (s == SS - 1) outv[row] = vn;
        }
    }

    // xc update (global) + stage new A1 into LDS (bf16)
    #pragma unroll
    for (int i = 0; i < 4; ++i) {
        int col = (wv + 4*i) * 16 + l15;
        #pragma unroll
        for (int r = 0; r < 4; ++r) {
            int row = row0 + quad * 4 + r;
            float xn = xcv[i][r] - grad[i][r] * h + srt * dwv[i][r];
            xc[(size_t)row * DD + col] = xn;
            if (doP1) As[(quad * 4 + r) * AS_STRIDE + col] = f2b(xn);
        }
    }
    if (!doP1) return;
    __syncthreads();

    // P1(s+1) GEMM: KT=8, NT=17, wave wv owns tiles wv+4i (i<5)
    f32x4 acc2[5];
    #pragma unroll
    for (int i = 0; i < 5; ++i) acc2[i] = (f32x4){0.f, 0.f, 0.f, 0.f};
    for (int kt = 0; kt < 8; ++kt) {
        short8 af = *(const short8*)(&As[l15 * AS_STRIDE + kt * 32 + quad * 8]);
        const ushort_t* wp = W1q + ((size_t)(kt * 17 + wv)) * 512 + lane * 8;
        #pragma unroll
        for (int i = 0; i < 5; ++i) {
            int t = wv + i * 4;
            if (t < 17) {
                short8 bf = *(const short8*)(wp + (size_t)i * 4 * 512);
                acc2[i] = __builtin_amdgcn_mfma_f32_16x16x32_bf16(af, bf, acc2[i], 0, 0, 0);
            }
        }
    }
    #pragma unroll
    for (int i = 0; i < 5; ++i) {
        int t = wv + i * 4;
        if (t >= 17) continue;
        int col = t * 16 + l15;
        float bj = (col < HH) ? b1n[col] : 0.f;
        float y0 = acc2[i][0] + bj, y1 = acc2[i][1] + bj;
        float y2 = acc2[i][2] + bj, y3 = acc2[i][3] + bj;
        Y1[(size_t)(row0 + quad*4 + 0) * HP + col] = y0;
        Y1[(size_t)(row0 + quad*4 + 1) * HP + col] = y1;
        Y1[(size_t)(row0 + quad*4 + 2) * HP + col] = y2;
        Y1[(size_t)(row0 + quad*4 + 3) * HP + col] = y3;
        float sp = y0 + y1 + y2 + y3;
        float sq = y0*y0 + y1*y1 + y2*y2 + y3*y3;
        sp += __shfl_xor(sp, 16); sp += __shfl_xor(sp, 32);
        sq += __shfl_xor(sq, 16); sq += __shfl_xor(sq, 32);
        if (quad == 0 && col < HH) {
            float* spp = stats_out + (bid & 7) * 544;
            atomicAdd(spp + col, sp);
            atomicAdd(spp + 272 + col, sq);
        }
    }
    #undef RED
}

// ---------------- v0 layer 3 (N=1), 128 blocks ----------------
__device__ __forceinline__ void dev_v0l3(
    int bid,
    const float* __restrict__ y2, const float* __restrict__ stats_in,
    const float* __restrict__ gv, const float* __restrict__ bev,
    const float* __restrict__ wv3, const float* __restrict__ bv3,
    float* __restrict__ vout, float* __restrict__ sv,
    float (*AC)[HP], float* __restrict__ XTRA)
{
    float* WC = XTRA;          // [HP]
    float* rv = XTRA + 288;    // [16]
    float* rq = XTRA + 304;    // [16]
    const int tid = threadIdx.x;

    compute_ac(stats_in, gv, bev, AC);
    for (int t = tid; t < HP; t += 256)
        WC[t] = (t < HH) ? wv3[t] : 0.0f;
    __syncthreads();

    const int r   = tid >> 4;
    const int ks  = tid & 15;
    const int row = bid * 16 + r;
    const int k0  = ks * 17;
    const int k1  = (k0 + 17 < HH) ? (k0 + 17) : HH;
    float acc = 0.0f;
    for (int k = k0; k < k1; ++k) {
        float y  = y2[(size_t)row * HP + k];
        float a2 = fmaxf(fmaf(AC[0][k], y, AC[1][k]), 0.0f);
        acc = fmaf(a2, WC[k], acc);
    }
    acc += __shfl_xor(acc, 1);
    acc += __shfl_xor(acc, 2);
    acc += __shfl_xor(acc, 4);
    acc += __shfl_xor(acc, 8);
    if (ks == 0) {
        float y = acc + bv3[0];
        vout[row] = y;
        rv[r] = y;
        rq[r] = y * y;
    }
    __syncthreads();
    if (tid == 0) {
        float s = 0.f, q = 0.f;
        #pragma unroll
        for (int i = 0; i < 16; ++i) { s += rv[i]; q += rq[i]; }
        atomicAdd(sv, s);
        atomicAdd(sv + 1, q);
    }
}

__device__ __forceinline__ void dev_v0fin(int bid, float* __restrict__ v,
                                          const float* __restrict__ sv,
                                          const float* __restrict__ gv3,
                                          const float* __restrict__ bev3) {
    int row = bid * 256 + threadIdx.x;
    float mu  = sv[0] * (1.0f / 2048.0f);
    float var = sv[1] * (1.0f / 2048.0f) - mu * mu;
    float rs  = rsqrtf(fmaxf(var, 0.0f) + BN_EPS);
    float y   = v[row];
    v[row] = fmaxf(gv3[0] * (y - mu) * rs + bev3[0], 0.0f);
}

// ---------------- the persistent kernel ----------------
__global__ __launch_bounds__(256, 1) void k_persist(
    const float* __restrict__ x, const float* __restrict__ dW,
    const float* __restrict__ law, const float* __restrict__ tg,
    const float* __restrict__ b1, const float* __restrict__ g1, const float* __restrict__ be1,
    const float* __restrict__ b2, const float* __restrict__ g2, const float* __restrict__ be2,
    const float* __restrict__ b3,
    const float* __restrict__ bv1, const float* __restrict__ gv1, const float* __restrict__ bev1,
    const float* __restrict__ bv2, const float* __restrict__ gv2, const float* __restrict__ bev2,
    const float* __restrict__ Wv3, const float* __restrict__ bv3,
    const float* __restrict__ gv3, const float* __restrict__ bev3,
    float* __restrict__ ws, float* __restrict__ out)
{
    __shared__ ushort_t As[16 * AS_STRIDE];   // 9472 B
    __shared__ float AC[2][HP];               // 2176 B
    __shared__ float XTRA[320];               // red (192) / WC+rv+rq (320)

    const int bid = blockIdx.x;
    const int tid = threadIdx.x;

    float* xc  = ws + XC_OFF;
    float* Y1  = ws + Y1_OFF;
    float* Y2  = ws + Y2_OFF;
    float* V   = ws + V_OFF;
    float* S1  = ws + S1_OFF;
    float* S2  = ws + S2_OFF;
    float* S1v = ws + S1V_OFF;
    float* S2v = ws + S2V_OFF;
    float* SV  = ws + SV_OFF;
    ushort_t* WQ = (ushort_t*)(ws + WQ_OFF);
    ushort_t* W1q  = WQ + W1Q_OFF;
    ushort_t* W2q  = WQ + W2Q_OFF;
    ushort_t* W3q  = WQ + W3Q_OFF;
    ushort_t* Wv1q = WQ + WV1Q_OFF;
    ushort_t* Wv2q = WQ + WV2Q_OFF;
    unsigned* bar  = (unsigned*)(ws + BAR_OFF);

    unsigned gen = 0;

    // ph0: xc = x; zero stat buffers (S1,S2,S1v,S2v,SV contiguous = 26128 f32)
    for (int idx = bid * 256 + tid; idx < BATCH * DD; idx += 65536)
        xc[idx] = x[idx];
    {
        int z = bid * 256 + tid;
        if (z < 26128) S1[z] = 0.0f;
    }
    grid_bar(bar, gen, bid); gen++;

    // ph1: v0 layer 1 (x @ Wv1), stats -> S1v
    dev_lin(bid, 0, 8, x, DD, nullptr, nullptr, nullptr,
            Wv1q, bv1, Y1, S1v, nullptr, As, AC);
    grid_bar(bar, gen, bid); gen++;

    // ph2: v0 layer 2 (relu(bn(Y1)) @ Wv2), stats -> S2v
    dev_lin(bid, 2, 9, Y1, HP, S1v, gv1, bev1,
            Wv2q, bv2, Y2, S2v, nullptr, As, AC);
    grid_bar(bar, gen, bid); gen++;

    // ph3: v0 layer 3 (N=1) -> V, SV
    if (bid < 128)
        dev_v0l3(bid, Y2, S2v, gv2, bev2, Wv3, bv3, V, SV, AC, XTRA);
    grid_bar(bar, gen, bid); gen++;

    // ph4: v0 final BN+relu on V (blocks 0-7)  +  P1(0): x @ W1[0], stats -> S1[0]
    if (bid < 8)
        dev_v0fin(bid, V, SV, gv3, bev3);
    dev_lin(bid, 0, 8, x, DD, nullptr, nullptr, nullptr,
            W1q, b1, Y1, S1, nullptr, As, AC);
    grid_bar(bar, gen, bid); gen++;

    // main loop: 2 phases (2 barriers) per step
    for (int s = 0; s < SS; ++s) {
        int p = s & 1;
        // P2: relu(bn(Y1)) @ W2[s] -> Y2, stats -> S2[p]; zero S1[1-p]
        dev_lin(bid, 2, 9, Y1, HP, S1 + p * 4352,
                g1 + s * HH, be1 + s * HH,
                W2q + (size_t)s * W2S, b2 + s * HH,
                Y2, S2 + p * 4352, S1 + (1 - p) * 4352, As, AC);
        grid_bar(bar, gen, bid); gen++;

        // F: P3 grad + v/xc update + P1(s+1), stats -> S1[1-p]; zero S2[1-p]
        int sn = (s + 1 < SS) ? s + 1 : 0;   // dummy valid ptrs when doP1==0
        if (bid < 128)
            dev_fused(bid, Y2, S2 + p * 4352,
                      g2 + s * HH, be2 + s * HH,
                      W3q + (size_t)s * W3S, b3 + s * DD,
                      law + s * DD, dW + (size_t)s * BATCH * DD,
                      tg, s, (s < SS - 1) ? 1 : 0,
                      xc, V, out,
                      W1q + (size_t)sn * W1S, b1 + sn * HH,
                      Y1, S1 + ((s + 1) & 1) * 4352,
                      S2 + (1 - p) * 4352, As, AC, XTRA);
        grid_bar(bar, gen, bid); gen++;
    }
}

extern "C" void kernel_launch(void* const* d_in, const int* in_sizes, int n_in,
                              void* d_out, int out_size, void* d_ws, size_t ws_size,
                              hipStream_t stream)
{
    (void)in_sizes; (void)n_in; (void)out_size; (void)ws_size;
    const float* x    = (const float*)d_in[0];
    const float* dW   = (const float*)d_in[1];
    const float* law  = (const float*)d_in[2];
    const float* tg   = (const float*)d_in[3];
    const float* W1   = (const float*)d_in[4];
    const float* b1   = (const float*)d_in[5];
    const float* g1   = (const float*)d_in[6];
    const float* be1  = (const float*)d_in[7];
    const float* W2   = (const float*)d_in[8];
    const float* b2   = (const float*)d_in[9];
    const float* g2   = (const float*)d_in[10];
    const float* be2  = (const float*)d_in[11];
    const float* W3   = (const float*)d_in[12];
    const float* b3   = (const float*)d_in[13];
    const float* Wv1  = (const float*)d_in[14];
    const float* bv1  = (const float*)d_in[15];
    const float* gv1  = (const float*)d_in[16];
    const float* bev1 = (const float*)d_in[17];
    const float* Wv2  = (const float*)d_in[18];
    const float* bv2  = (const float*)d_in[19];
    const float* gv2  = (const float*)d_in[20];
    const float* bev2 = (const float*)d_in[21];
    const float* Wv3  = (const float*)d_in[22];
    const float* bv3  = (const float*)d_in[23];
    const float* gv3  = (const float*)d_in[24];
    const float* bev3 = (const float*)d_in[25];

    float* ws = (float*)d_ws;
    ushort_t* WQ = (ushort_t*)(ws + WQ_OFF);
    ushort_t* W1q  = WQ + W1Q_OFF;
    ushort_t* W2q  = WQ + W2Q_OFF;
    ushort_t* W3q  = WQ + W3Q_OFF;
    ushort_t* Wv1q = WQ + WV1Q_OFF;
    ushort_t* Wv2q = WQ + WV2Q_OFF;
    float* out = (float*)d_out;

    k_pre<<<1, 256, 0, stream>>>(ws);
    k_conv<<<13600, 256, 0, stream>>>(W1,  W1q,  DD, HH, 8, 17, (long)SS * W1S);
    k_conv<<<15300, 256, 0, stream>>>(W2,  W2q,  HH, HH, 9, 17, (long)SS * W2S);
    k_conv<<<14400, 256, 0, stream>>>(W3,  W3q,  HH, DD, 9, 16, (long)SS * W3S);
    k_conv<<<272,   256, 0, stream>>>(Wv1, Wv1q, DD, HH, 8, 17, (long)W1S);
    k_conv<<<306,   256, 0, stream>>>(Wv2, Wv2q, HH, HH, 9, 17, (long)W2S);

    k_persist<<<256, 256, 0, stream>>>(
        x, dW, law, tg,
        b1, g1, be1, b2, g2, be2, b3,
        bv1, gv1, bev1, bv2, gv2, bev2,
        Wv3, bv3, gv3, bev3,
        ws, out);
}

// Round 3
// 1393.785 us; speedup vs baseline: 2.1069x; 2.1069x over previous
//
#include <hip/hip_runtime.h>
#include <hip/hip_bf16.h>

// B=2048, D=256, H=266 (pad N->272, K->288), S=50. All f32 I/O; bf16 MFMA inside.
// PERSISTENT KERNEL, BLOCK-PRIVATE ACTIVATIONS:
//   256 blocks x 512 threads; block b owns batch rows [8b,8b+8) for the whole
//   run, so xc/Y1/Y2/V/out are block-private (plain cached access, no fences).
//   Only BN stats + barrier words cross blocks: stats via LLC atomicAdd /
//   atomicExch (RMW at coherence point), read with agent-scope atomic loads.
//   Grid barrier = MONOTONIC two-level atomic tree (no resets -> no lost-update
//   race), NO cache invalidate/writeback -> weights stay hot across phases.

#define BATCH 2048
#define DD    256
#define HH    266
#define HP    272
#define SS    50
#define BN_EPS 1e-5f
#define SIG   0.3f
#define AS_STRIDE 296   // LDS A-tile row stride in bf16 elements

// f32 workspace offsets
#define XC_OFF 0              // [2048][256]
#define Y1_OFF 524288         // [2048][272]
#define Y2_OFF 1081344        // [2048][272]
#define V_OFF  1638400        // [2048]
#define S1_OFF 1640448        // 2 parity x 8 reps x 544
#define S2_OFF 1649152
#define S1V_OFF 1657856       // 8 x 544
#define S2V_OFF 1662208
#define SV_OFF  1666560       // 16
#define WQ_OFF  1666576       // bf16 region starts here (16B aligned)

// swizzled weight strides (ushort units)
#define W1S 69632   // 8kt*17nt*512
#define W2S 78336   // 9*17*512
#define W3S 73728   // 9*16*512
#define W1Q_OFF 0
#define W2Q_OFF 3481600
#define W3Q_OFF 7398400
#define WV1Q_OFF 11084800
#define WV2Q_OFF 11154432

// barrier state: u32[512] at f32 index BAR_OFF
#define BAR_OFF 7283200

typedef unsigned short ushort_t;
using short8 = __attribute__((ext_vector_type(8))) short;
using f32x4  = __attribute__((ext_vector_type(4))) float;

__device__ __forceinline__ ushort_t f2b(float f) {   // f32 -> bf16 bits, RNE
    unsigned u = __float_as_uint(f);
    unsigned r = u + 0x7FFF + ((u >> 16) & 1);
    return (ushort_t)(r >> 16);
}

// coherent load (bypasses non-coherent L1/L2 via agent-scope atomic lowering)
__device__ __forceinline__ float ld_coh(const float* p) {
    return __hip_atomic_load((const float*)p, __ATOMIC_RELAXED, __HIP_MEMORY_SCOPE_AGENT);
}

// read-only prefetch (plain cached load, sunk into a dummy use)
__device__ __forceinline__ void prefetch16(const void* p, int n16, int tid) {
    const f32x4* q = (const f32x4*)p;
    for (int i = tid; i < n16; i += 512) {
        f32x4 t = q[i];
        asm volatile("" :: "v"(t));
    }
}

// ---------------- weight swizzle: f32 [K][N] -> bf16 B-frag layout ----------------
__global__ __launch_bounds__(256) void k_conv(const float* __restrict__ src,
                                              ushort_t* __restrict__ dst,
                                              int K, int N, int KT, int NT,
                                              long total) {
    long t = (long)blockIdx.x * 256 + threadIdx.x;
    if (t >= total) return;
    int per = KT * NT * 512;
    int step = (int)(t / per);
    int e = (int)(t - (long)step * per);
    int kt = e / (NT * 512);
    int r = e - kt * NT * 512;
    int nt = r / 512;
    int r2 = r & 511;
    int lane = r2 >> 3;
    int j = r2 & 7;
    int k = kt * 32 + (lane >> 4) * 8 + j;
    int n = nt * 16 + (lane & 15);
    float v = (k < K && n < N) ? src[(size_t)step * K * N + (size_t)k * N + n] : 0.f;
    dst[t] = f2b(v);
}

// ---------------- barrier pre-init (ws is poisoned between iterations) ----
__global__ __launch_bounds__(256) void k_pre(float* __restrict__ ws) {
    unsigned* bar = (unsigned*)(ws + BAR_OFF);
    for (int i = threadIdx.x; i < 512; i += 256) atomicExch(bar + i, 0u);
}

// ---------------- grid barrier: MONOTONIC two-level atomic tree ----------------
// No resets: leaf/root/rel only ever increase, so in-flight ops can never wipe
// a later arrival (the R2 deadlock). __syncthreads() drains each wave's own
// vmcnt before arrival, so all stores/atomics of this block are complete.
// Cross-block data is only read via LLC atomics, so no cache fences needed.
__device__ __forceinline__ void grid_bar(unsigned* bar, unsigned gen, int bid) {
    __syncthreads();
    if (threadIdx.x == 0) {
        unsigned* leaf = bar + (bid & 7) * 32;   // 8 leaves, 128B apart
        unsigned* root = bar + 256;
        unsigned* rel  = bar + 288;
        bool done = false;
        unsigned a = __hip_atomic_fetch_add(leaf, 1u, __ATOMIC_RELAXED, __HIP_MEMORY_SCOPE_AGENT);
        if (a == gen * 32u + 31u) {
            unsigned r = __hip_atomic_fetch_add(root, 1u, __ATOMIC_RELAXED, __HIP_MEMORY_SCOPE_AGENT);
            if (r == gen * 8u + 7u) {
                __hip_atomic_store(rel, gen + 1u, __ATOMIC_RELAXED, __HIP_MEMORY_SCOPE_AGENT);
                done = true;
            }
        }
        if (!done) {
            while (__hip_atomic_load(rel, __ATOMIC_RELAXED, __HIP_MEMORY_SCOPE_AGENT) < gen + 1u)
                __builtin_amdgcn_s_sleep(1);
        }
        asm volatile("" ::: "memory");
    }
    __syncthreads();
}

// BN affine constants from LLC-coherent stat reads: A = relu(a*y + c)
__device__ __forceinline__ void compute_ac_coh(const float* __restrict__ si,
                                               const float* __restrict__ g,
                                               const float* __restrict__ be,
                                               float (*AC)[HP]) {
    int t = threadIdx.x;
    if (t < HP) {
        float a = 0.f, c = 0.f;
        if (t < HH) {
            float s = 0.f, q = 0.f;
            #pragma unroll
            for (int r = 0; r < 8; ++r) {
                s += ld_coh(si + r * 544 + t);
                q += ld_coh(si + r * 544 + 272 + t);
            }
            float mu  = s * (1.0f / 2048.0f);
            float var = q * (1.0f / 2048.0f) - mu * mu;
            float rs  = rsqrtf(fmaxf(var, 0.0f) + BN_EPS);
            a = g[t] * rs;
            c = be[t] - mu * a;
        }
        AC[0][t] = a;
        AC[1][t] = c;
    }
}

// ---------------- phase: [affine-relu] GEMM, NT=17, 8 rows/block ----------------
// mode 0: raw f32 xsrc; mode 2: affine(stats) on Y. All 256 blocks, full N.
__device__ __forceinline__ void dev_lin8(
    int bid, int mode, int KT, const float* __restrict__ xsrc, int xld,
    const float* __restrict__ stats_in, const float* __restrict__ g,
    const float* __restrict__ be,
    const ushort_t* __restrict__ Wq, const float* __restrict__ bias,
    float* __restrict__ yout, float* __restrict__ stats_out,
    float* __restrict__ zero_ptr,
    ushort_t* __restrict__ As, float (*AC)[HP])
{
    const int tid  = threadIdx.x;
    const int lane = tid & 63;
    const int wv   = tid >> 6;
    const int quad = lane >> 4;
    const int l15  = lane & 15;
    const int row0 = bid * 8;

    if (zero_ptr != nullptr) {
        int z = bid * 512 + tid;
        if (z < 4352) atomicExch(zero_ptr + z, 0.0f);
    }

    if (mode == 2) { compute_ac_coh(stats_in, g, be, AC); __syncthreads(); }

    const int PAIRS = KT * 16;
    for (int idx = tid; idx < 8 * PAIRS; idx += 512) {
        int m  = idx / PAIRS;
        int kk = (idx - m * PAIRS) * 2;
        float v0, v1;
        if (mode == 2) {
            v0 = (kk < HH)   ? fmaxf(fmaf(AC[0][kk],   xsrc[(size_t)(row0+m)*xld + kk],   AC[1][kk]),   0.f) : 0.f;
            v1 = (kk+1 < HH) ? fmaxf(fmaf(AC[0][kk+1], xsrc[(size_t)(row0+m)*xld + kk+1], AC[1][kk+1]), 0.f) : 0.f;
        } else {
            v0 = xsrc[(size_t)(row0+m)*xld + kk];
            v1 = xsrc[(size_t)(row0+m)*xld + kk + 1];
        }
        ((unsigned int*)As)[m * (AS_STRIDE/2) + (kk >> 1)] =
            (unsigned int)f2b(v0) | ((unsigned int)f2b(v1) << 16);
    }
    __syncthreads();

    // tiles t = wv + 8*i (i<2 for all waves; i==2 only wv==0 -> t=16)
    f32x4 acc[3];
    #pragma unroll
    for (int i = 0; i < 3; ++i) acc[i] = (f32x4){0.f, 0.f, 0.f, 0.f};

    for (int kt = 0; kt < KT; ++kt) {
        short8 af = *(const short8*)(&As[l15 * AS_STRIDE + kt * 32 + quad * 8]);
        const ushort_t* wp = Wq + ((size_t)(kt * 17 + wv)) * 512 + lane * 8;
        #pragma unroll
        for (int i = 0; i < 3; ++i) {
            if (i < 2 || wv == 0) {
                short8 bf = *(const short8*)(wp + (size_t)i * 8 * 512);
                acc[i] = __builtin_amdgcn_mfma_f32_16x16x32_bf16(af, bf, acc[i], 0, 0, 0);
            }
        }
    }

    #pragma unroll
    for (int i = 0; i < 3; ++i) {
        if (i == 2 && wv != 0) continue;
        int t = wv + 8 * i;
        int col = t * 16 + l15;
        float bj = (col < HH) ? bias[col] : 0.f;
        float y0 = acc[i][0] + bj, y1 = acc[i][1] + bj;
        float y2 = acc[i][2] + bj, y3 = acc[i][3] + bj;
        if (quad < 2) {
            yout[(size_t)(row0 + quad*4 + 0) * HP + col] = y0;
            yout[(size_t)(row0 + quad*4 + 1) * HP + col] = y1;
            yout[(size_t)(row0 + quad*4 + 2) * HP + col] = y2;
            yout[(size_t)(row0 + quad*4 + 3) * HP + col] = y3;
        }
        float sp = (quad < 2) ? (y0 + y1 + y2 + y3) : 0.f;
        float sq = (quad < 2) ? (y0*y0 + y1*y1 + y2*y2 + y3*y3) : 0.f;
        sp += __shfl_xor(sp, 16); sp += __shfl_xor(sp, 32);
        sq += __shfl_xor(sq, 16); sq += __shfl_xor(sq, 32);
        if (quad == 0 && col < HH) {
            float* spp = stats_out + (bid & 7) * 544;
            atomicAdd(spp + col, sp);
            atomicAdd(spp + 272 + col, sq);
        }
    }
}

// ---------------- phase: P3 grad GEMM + v/xc update + P1(s+1) GEMM --------------
__device__ __forceinline__ void dev_fused8(
    int bid,
    const float* __restrict__ y2g, const float* __restrict__ stats_in,
    const float* __restrict__ g2, const float* __restrict__ be2,
    const ushort_t* __restrict__ W3q, const float* __restrict__ b3,
    const float* __restrict__ law, const float* __restrict__ dWs,
    const float* __restrict__ tg, int s, int doP1,
    float* __restrict__ xc, float* __restrict__ vv, float* __restrict__ outv,
    const ushort_t* __restrict__ W1q, const float* __restrict__ b1n,
    float* __restrict__ Y1, float* __restrict__ stats_out,
    float* __restrict__ zero_ptr,
    ushort_t* __restrict__ As, float (*AC)[HP], float* __restrict__ red)
{
    const int tid  = threadIdx.x;
    const int lane = tid & 63;
    const int wv   = tid >> 6;
    const int quad = lane >> 4;
    const int l15  = lane & 15;
    const int row0 = bid * 8;

    if (zero_ptr != nullptr) {
        int z = bid * 512 + tid;
        if (z < 4352) atomicExch(zero_ptr + z, 0.0f);
    }

    compute_ac_coh(stats_in, g2, be2, AC);
    __syncthreads();

    // stage A2 = relu(affine(Y2)): 8 rows x 288 (K padded)
    for (int idx = tid; idx < 8 * 144; idx += 512) {
        int m  = idx / 144;
        int kk = (idx - m * 144) * 2;
        float v0 = (kk < HH)   ? fmaxf(fmaf(AC[0][kk],   y2g[(size_t)(row0+m)*HP + kk],   AC[1][kk]),   0.f) : 0.f;
        float v1 = (kk+1 < HH) ? fmaxf(fmaf(AC[0][kk+1], y2g[(size_t)(row0+m)*HP + kk+1], AC[1][kk+1]), 0.f) : 0.f;
        ((unsigned int*)As)[m * (AS_STRIDE/2) + (kk >> 1)] =
            (unsigned int)f2b(v0) | ((unsigned int)f2b(v1) << 16);
    }
    __syncthreads();

    // P3 GEMM: KT=9, NT=16, tiles t = wv, wv+8
    f32x4 acc[2];
    acc[0] = (f32x4){0.f,0.f,0.f,0.f};
    acc[1] = (f32x4){0.f,0.f,0.f,0.f};
    for (int kt = 0; kt < 9; ++kt) {
        short8 af = *(const short8*)(&As[l15 * AS_STRIDE + kt * 32 + quad * 8]);
        const ushort_t* wp = W3q + ((size_t)(kt * 16 + wv)) * 512 + lane * 8;
        acc[0] = __builtin_amdgcn_mfma_f32_16x16x32_bf16(af, *(const short8*)(wp),           acc[0], 0, 0, 0);
        acc[1] = __builtin_amdgcn_mfma_f32_16x16x32_bf16(af, *(const short8*)(wp + 8 * 512), acc[1], 0, 0, 0);
    }

    // epilogue: grad, row partials (rows valid only for quad<2)
    const float h   = tg[s + 1] - tg[s];
    const float srt = SIG * sqrtf(h);
    float grad[2][4], xcv[2][4], dwv[2][4];
    float sxr[4] = {0,0,0,0}, sgr[4] = {0,0,0,0}, sgnr[4] = {0,0,0,0};
    #pragma unroll
    for (int i = 0; i < 2; ++i) {
        int col = (wv + 8*i) * 16 + l15;
        #pragma unroll
        for (int r = 0; r < 4; ++r) {
            float gd = acc[i][r] + b3[col];
            grad[i][r] = gd;
            xcv[i][r] = 0.f; dwv[i][r] = 0.f;
            if (quad < 2) {
                int row = row0 + quad * 4 + r;
                float xv = xc[(size_t)row * DD + col];
                float dw = dWs[(size_t)row * DD + col];
                float d  = xv - law[col];
                xcv[i][r] = xv; dwv[i][r] = dw;
                sxr[r]  = fmaf(d, d, sxr[r]);
                sgr[r]  = fmaf(gd, gd, sgr[r]);
                sgnr[r] = fmaf(gd, dw, sgnr[r]);
            }
        }
    }
    #pragma unroll
    for (int off = 1; off < 16; off <<= 1) {
        #pragma unroll
        for (int r = 0; r < 4; ++r) {
            sxr[r]  += __shfl_xor(sxr[r],  off);
            sgr[r]  += __shfl_xor(sgr[r],  off);
            sgnr[r] += __shfl_xor(sgnr[r], off);
        }
    }
    if (l15 == 0 && quad < 2) {
        #pragma unroll
        for (int r = 0; r < 4; ++r) {
            int rr = quad * 4 + r;
            red[(wv * 8 + rr) * 3 + 0] = sxr[r];
            red[(wv * 8 + rr) * 3 + 1] = sgr[r];
            red[(wv * 8 + rr) * 3 + 2] = sgnr[r];
        }
    }
    __syncthreads();   // red ready; all waves done reading As (P3)

    if (tid < 8) {
        float sx = 0.f, sg = 0.f, sgn = 0.f;
        #pragma unroll
        for (int w = 0; w < 8; ++w) {
            sx  += red[(w * 8 + tid) * 3 + 0];
            sg  += red[(w * 8 + tid) * 3 + 1];
            sgn += red[(w * 8 + tid) * 3 + 2];
        }
        int row = row0 + tid;
        float f  = 0.5f * (sx + sg);
        float vn = vv[row] - f * h + srt * sgn;
        vv[row] = vn;
        if (s == SS - 1) outv[row] = vn;
    }

    // xc update + stage new A1 (bf16) rows 0-7
    #pragma unroll
    for (int i = 0; i < 2; ++i) {
        int col = (wv + 8*i) * 16 + l15;
        if (quad < 2) {
            #pragma unroll
            for (int r = 0; r < 4; ++r) {
                int row = row0 + quad * 4 + r;
                float xn = xcv[i][r] - grad[i][r] * h + srt * dwv[i][r];
                xc[(size_t)row * DD + col] = xn;
                if (doP1) As[(quad * 4 + r) * AS_STRIDE + col] = f2b(xn);
            }
        }
    }
    if (!doP1) return;
    __syncthreads();

    // P1(s+1) GEMM: KT=8, NT=17
    f32x4 acc2[3];
    #pragma unroll
    for (int i = 0; i < 3; ++i) acc2[i] = (f32x4){0.f, 0.f, 0.f, 0.f};
    for (int kt = 0; kt < 8; ++kt) {
        short8 af = *(const short8*)(&As[l15 * AS_STRIDE + kt * 32 + quad * 8]);
        const ushort_t* wp = W1q + ((size_t)(kt * 17 + wv)) * 512 + lane * 8;
        #pragma unroll
        for (int i = 0; i < 3; ++i) {
            if (i < 2 || wv == 0) {
                short8 bf = *(const short8*)(wp + (size_t)i * 8 * 512);
                acc2[i] = __builtin_amdgcn_mfma_f32_16x16x32_bf16(af, bf, acc2[i], 0, 0, 0);
            }
        }
    }
    #pragma unroll
    for (int i = 0; i < 3; ++i) {
        if (i == 2 && wv != 0) continue;
        int t = wv + 8 * i;
        int col = t * 16 + l15;
        float bj = (col < HH) ? b1n[col] : 0.f;
        float y0 = acc2[i][0] + bj, y1 = acc2[i][1] + bj;
        float y2 = acc2[i][2] + bj, y3 = acc2[i][3] + bj;
        if (quad < 2) {
            Y1[(size_t)(row0 + quad*4 + 0) * HP + col] = y0;
            Y1[(size_t)(row0 + quad*4 + 1) * HP + col] = y1;
            Y1[(size_t)(row0 + quad*4 + 2) * HP + col] = y2;
            Y1[(size_t)(row0 + quad*4 + 3) * HP + col] = y3;
        }
        float sp = (quad < 2) ? (y0 + y1 + y2 + y3) : 0.f;
        float sq = (quad < 2) ? (y0*y0 + y1*y1 + y2*y2 + y3*y3) : 0.f;
        sp += __shfl_xor(sp, 16); sp += __shfl_xor(sp, 32);
        sq += __shfl_xor(sq, 16); sq += __shfl_xor(sq, 32);
        if (quad == 0 && col < HH) {
            float* spp = stats_out + (bid & 7) * 544;
            atomicAdd(spp + col, sp);
            atomicAdd(spp + 272 + col, sq);
        }
    }
}

// ---------------- v0 layer 3 (N=1), 8 rows/block, one wave per row -------------
__device__ __forceinline__ void dev_v0l3_8(
    int bid, const float* __restrict__ y2, const float* __restrict__ stats_in,
    const float* __restrict__ gv, const float* __restrict__ bev,
    const float* __restrict__ wv3, const float* __restrict__ bv3,
    float* __restrict__ vout, float* __restrict__ sv,
    float (*AC)[HP], float* __restrict__ xtra)
{
    const int tid = threadIdx.x;
    compute_ac_coh(stats_in, gv, bev, AC);
    __syncthreads();

    const int r   = tid >> 6;           // 0..7 (one wave per row)
    const int ln  = tid & 63;
    const int row = bid * 8 + r;
    int k0 = ln * 5, k1 = k0 + 5;
    if (k1 > HH) k1 = HH;
    float acc = 0.0f;
    for (int k = k0; k < k1; ++k) {
        float y  = y2[(size_t)row * HP + k];
        float a2 = fmaxf(fmaf(AC[0][k], y, AC[1][k]), 0.0f);
        acc = fmaf(a2, wv3[k], acc);
    }
    #pragma unroll
    for (int off = 1; off < 64; off <<= 1) acc += __shfl_xor(acc, off);
    if (ln == 0) {
        float y = acc + bv3[0];
        vout[row] = y;
        xtra[r] = y;
        xtra[8 + r] = y * y;
    }
    __syncthreads();
    if (tid == 0) {
        float s = 0.f, q = 0.f;
        #pragma unroll
        for (int i = 0; i < 8; ++i) { s += xtra[i]; q += xtra[8 + i]; }
        atomicAdd(sv, s);
        atomicAdd(sv + 1, q);
    }
}

__device__ __forceinline__ void dev_v0fin8(int bid, float* __restrict__ v,
                                           const float* __restrict__ sv,
                                           const float* __restrict__ gv3,
                                           const float* __restrict__ bev3) {
    if (threadIdx.x < 8) {
        float s0 = ld_coh(sv);
        float s1 = ld_coh(sv + 1);
        float mu  = s0 * (1.0f / 2048.0f);
        float var = s1 * (1.0f / 2048.0f) - mu * mu;
        float rs  = rsqrtf(fmaxf(var, 0.0f) + BN_EPS);
        int row = bid * 8 + threadIdx.x;
        float y = v[row];
        v[row] = fmaxf(gv3[0] * (y - mu) * rs + bev3[0], 0.0f);
    }
}

// ---------------- the persistent kernel ----------------
__global__ __launch_bounds__(512) void k_persist(
    const float* __restrict__ x, const float* __restrict__ dW,
    const float* __restrict__ law, const float* __restrict__ tg,
    const float* __restrict__ b1, const float* __restrict__ g1, const float* __restrict__ be1,
    const float* __restrict__ b2, const float* __restrict__ g2, const float* __restrict__ be2,
    const float* __restrict__ b3,
    const float* __restrict__ bv1, const float* __restrict__ gv1, const float* __restrict__ bev1,
    const float* __restrict__ bv2, const float* __restrict__ gv2, const float* __restrict__ bev2,
    const float* __restrict__ Wv3, const float* __restrict__ bv3,
    const float* __restrict__ gv3, const float* __restrict__ bev3,
    float* __restrict__ ws, float* __restrict__ out)
{
    __shared__ ushort_t As[16 * AS_STRIDE];   // 9472 B (rows 8-15 stay zero)
    __shared__ float AC[2][HP];               // 2176 B
    __shared__ float XTRA[256];               // red[8][8][3] / v0l3 partials

    const int bid = blockIdx.x;
    const int tid = threadIdx.x;

    float* xc  = ws + XC_OFF;
    float* Y1  = ws + Y1_OFF;
    float* Y2  = ws + Y2_OFF;
    float* V   = ws + V_OFF;
    float* S1  = ws + S1_OFF;
    float* S2  = ws + S2_OFF;
    float* S1v = ws + S1V_OFF;
    float* S2v = ws + S2V_OFF;
    float* SV  = ws + SV_OFF;
    ushort_t* WQ = (ushort_t*)(ws + WQ_OFF);
    ushort_t* W1q  = WQ + W1Q_OFF;
    ushort_t* W2q  = WQ + W2Q_OFF;
    ushort_t* W3q  = WQ + W3Q_OFF;
    ushort_t* Wv1q = WQ + WV1Q_OFF;
    ushort_t* Wv2q = WQ + WV2Q_OFF;
    unsigned* bar  = (unsigned*)(ws + BAR_OFF);

    unsigned gen = 0;
    const int sl = (bid >> 3) & 31;   // weight-prefetch slice (per-XCD coverage)

    // ph0: xc = x (private rows); zero stat buffers (LLC RMW); zero As rows 8-15.
    for (int i = tid; i < 2048; i += 512)
        xc[bid * 2048 + i] = x[bid * 2048 + i];
    {
        int z = bid * 512 + tid;
        if (z < 26128) atomicExch(S1 + z, 0.0f);
    }
    for (int i = tid; i < 8 * AS_STRIDE; i += 512)
        As[8 * AS_STRIDE + i] = 0;
    grid_bar(bar, gen, bid); gen++;

    // ph1: v0 layer 1 (x @ Wv1), stats -> S1v
    dev_lin8(bid, 0, 8, x, DD, nullptr, nullptr, nullptr,
             Wv1q, bv1, Y1, S1v, nullptr, As, AC);
    grid_bar(bar, gen, bid); gen++;

    // ph2: v0 layer 2 (relu(bn(Y1)) @ Wv2), stats -> S2v
    dev_lin8(bid, 2, 9, Y1, HP, S1v, gv1, bev1,
             Wv2q, bv2, Y2, S2v, nullptr, As, AC);
    grid_bar(bar, gen, bid); gen++;

    // ph3: v0 layer 3 (N=1) -> V, SV
    dev_v0l3_8(bid, Y2, S2v, gv2, bev2, Wv3, bv3, V, SV, AC, XTRA);
    grid_bar(bar, gen, bid); gen++;

    // ph4: v0 final BN+relu on V + P1(0): x @ W1[0] -> Y1, stats -> S1[0]
    dev_v0fin8(bid, V, SV, gv3, bev3);
    dev_lin8(bid, 0, 8, x, DD, nullptr, nullptr, nullptr,
             W1q, b1, Y1, S1, nullptr, As, AC);
    // prefetch W2(0) for P2(0) while waiting
    prefetch16((const char*)W2q + sl * 4896, 306, tid);
    grid_bar(bar, gen, bid); gen++;

    // main loop: 2 phases (2 barriers) per step
    for (int s = 0; s < SS; ++s) {
        int p = s & 1;
        // P2: relu(bn(Y1)) @ W2[s] -> Y2, stats -> S2[p]; zero S1[1-p]
        dev_lin8(bid, 2, 9, Y1, HP, S1 + p * 4352,
                 g1 + s * HH, be1 + s * HH,
                 W2q + (size_t)s * W2S, b2 + s * HH,
                 Y2, S2 + p * 4352, S1 + (1 - p) * 4352, As, AC);
        // prefetch F(s) inputs while waiting: dW slice (private), W3(s), W1(s+1)
        prefetch16(dW + (size_t)s * BATCH * DD + (size_t)bid * 2048, 512, tid);
        prefetch16((const char*)(W3q + (size_t)s * W3S) + sl * 4608, 288, tid);
        if (s + 1 < SS)
            prefetch16((const char*)(W1q + (size_t)(s + 1) * W1S) + sl * 4352, 272, tid);
        grid_bar(bar, gen, bid); gen++;

        // F: P3 grad + v/xc update + P1(s+1), stats -> S1[1-p]; zero S2[1-p]
        int sn = (s + 1 < SS) ? s + 1 : 0;   // dummy valid ptrs when doP1==0
        dev_fused8(bid, Y2, S2 + p * 4352,
                   g2 + s * HH, be2 + s * HH,
                   W3q + (size_t)s * W3S, b3 + s * DD,
                   law + s * DD, dW + (size_t)s * BATCH * DD,
                   tg, s, (s < SS - 1) ? 1 : 0,
                   xc, V, out,
                   W1q + (size_t)sn * W1S, b1 + sn * HH,
                   Y1, S1 + ((s + 1) & 1) * 4352,
                   S2 + (1 - p) * 4352, As, AC, XTRA);
        // prefetch W2(s+1) for next P2 while waiting
        if (s + 1 < SS)
            prefetch16((const char*)(W2q + (size_t)(s + 1) * W2S) + sl * 4896, 306, tid);
        grid_bar(bar, gen, bid); gen++;
    }
}

extern "C" void kernel_launch(void* const* d_in, const int* in_sizes, int n_in,
                              void* d_out, int out_size, void* d_ws, size_t ws_size,
                              hipStream_t stream)
{
    (void)in_sizes; (void)n_in; (void)out_size; (void)ws_size;
    const float* x    = (const float*)d_in[0];
    const float* dW   = (const float*)d_in[1];
    const float* law  = (const float*)d_in[2];
    const float* tg   = (const float*)d_in[3];
    const float* W1   = (const float*)d_in[4];
    const float* b1   = (const float*)d_in[5];
    const float* g1   = (const float*)d_in[6];
    const float* be1  = (const float*)d_in[7];
    const float* W2   = (const float*)d_in[8];
    const float* b2   = (const float*)d_in[9];
    const float* g2   = (const float*)d_in[10];
    const float* be2  = (const float*)d_in[11];
    const float* W3   = (const float*)d_in[12];
    const float* b3   = (const float*)d_in[13];
    const float* Wv1  = (const float*)d_in[14];
    const float* bv1  = (const float*)d_in[15];
    const float* gv1  = (const float*)d_in[16];
    const float* bev1 = (const float*)d_in[17];
    const float* Wv2  = (const float*)d_in[18];
    const float* bv2  = (const float*)d_in[19];
    const float* gv2  = (const float*)d_in[20];
    const float* bev2 = (const float*)d_in[21];
    const float* Wv3  = (const float*)d_in[22];
    const float* bv3  = (const float*)d_in[23];
    const float* gv3  = (const float*)d_in[24];
    const float* bev3 = (const float*)d_in[25];

    float* ws = (float*)d_ws;
    ushort_t* WQ = (ushort_t*)(ws + WQ_OFF);
    ushort_t* W1q  = WQ + W1Q_OFF;
    ushort_t* W2q  = WQ + W2Q_OFF;
    ushort_t* W3q  = WQ + W3Q_OFF;
    ushort_t* Wv1q = WQ + WV1Q_OFF;
    ushort_t* Wv2q = WQ + WV2Q_OFF;
    float* out = (float*)d_out;

    k_pre<<<1, 256, 0, stream>>>(ws);
    k_conv<<<13600, 256, 0, stream>>>(W1,  W1q,  DD, HH, 8, 17, (long)SS * W1S);
    k_conv<<<15300, 256, 0, stream>>>(W2,  W2q,  HH, HH, 9, 17, (long)SS * W2S);
    k_conv<<<14400, 256, 0, stream>>>(W3,  W3q,  HH, DD, 9, 16, (long)SS * W3S);
    k_conv<<<272,   256, 0, stream>>>(Wv1, Wv1q, DD, HH, 8, 17, (long)W1S);
    k_conv<<<306,   256, 0, stream>>>(Wv2, Wv2q, HH, HH, 9, 17, (long)W2S);

    k_persist<<<256, 512, 0, stream>>>(
        x, dW, law, tg,
        b1, g1, be1, b2, g2, be2, b3,
        bv1, gv1, bev1, bv2, gv2, bev2,
        Wv3, bv3, gv3, bev3,
        ws, out);
}

// Round 4
// 1318.513 us; speedup vs baseline: 2.2272x; 1.0571x over previous
//
#include <hip/hip_runtime.h>
#include <hip/hip_bf16.h>

// B=2048, D=256, H=266 (pad N->272, K->288), S=50. All f32 I/O; bf16 MFMA inside.
// PERSISTENT KERNEL v3: 128 blocks x 512 threads; block b owns batch rows
// [16b,16b+16) for the whole run. Y1/Y2/xc live in LDS (block-private, no
// global round trips). Only BN stats + barrier words cross blocks: stats via
// LLC atomicAdd/atomicExch, read with agent-scope atomic loads. Grid barrier =
// MONOTONIC two-level atomic tree (no resets), no cache maintenance -> weights
// stay hot in L1/L2 across all 105 phases.

#define BATCH 2048
#define DD    256
#define HH    266
#define HP    272
#define SS    50
#define BN_EPS 1e-5f
#define SIG   0.3f
#define AS_STRIDE 296   // LDS A-tile row stride in bf16 elements

// f32 workspace offsets (Y1/Y2/XC regions now unused but offsets retained)
#define XC_OFF 0
#define Y1_OFF 524288
#define Y2_OFF 1081344
#define V_OFF  1638400        // [2048]
#define S1_OFF 1640448        // 2 parity x 8 reps x 544
#define S2_OFF 1649152
#define S1V_OFF 1657856       // 8 x 544
#define S2V_OFF 1662208
#define SV_OFF  1666560       // 16
#define WQ_OFF  1666576       // bf16 region starts here (16B aligned)

// swizzled weight strides (ushort units)
#define W1S 69632   // 8kt*17nt*512
#define W2S 78336   // 9*17*512
#define W3S 73728   // 9*16*512
#define W1Q_OFF 0
#define W2Q_OFF 3481600
#define W3Q_OFF 7398400
#define WV1Q_OFF 11084800
#define WV2Q_OFF 11154432

// barrier state: u32[512] at f32 index BAR_OFF
#define BAR_OFF 7283200

typedef unsigned short ushort_t;
using short8 = __attribute__((ext_vector_type(8))) short;
using f32x4  = __attribute__((ext_vector_type(4))) float;

__device__ __forceinline__ ushort_t f2b(float f) {   // f32 -> bf16 bits, RNE
    unsigned u = __float_as_uint(f);
    unsigned r = u + 0x7FFF + ((u >> 16) & 1);
    return (ushort_t)(r >> 16);
}

// coherent load (bypasses non-coherent L1/L2 via agent-scope atomic lowering)
__device__ __forceinline__ float ld_coh(const float* p) {
    return __hip_atomic_load((const float*)p, __ATOMIC_RELAXED, __HIP_MEMORY_SCOPE_AGENT);
}

// read-only prefetch (plain cached load, sunk into a dummy use)
__device__ __forceinline__ void prefetch16(const void* p, int n16, int tid) {
    const f32x4* q = (const f32x4*)p;
    for (int i = tid; i < n16; i += 512) {
        f32x4 t = q[i];
        asm volatile("" :: "v"(t));
    }
}

// ---------------- weight swizzle: f32 [K][N] -> bf16 B-frag layout ----------------
__global__ __launch_bounds__(256) void k_conv(const float* __restrict__ src,
                                              ushort_t* __restrict__ dst,
                                              int K, int N, int KT, int NT,
                                              long total) {
    long t = (long)blockIdx.x * 256 + threadIdx.x;
    if (t >= total) return;
    int per = KT * NT * 512;
    int step = (int)(t / per);
    int e = (int)(t - (long)step * per);
    int kt = e / (NT * 512);
    int r = e - kt * NT * 512;
    int nt = r / 512;
    int r2 = r & 511;
    int lane = r2 >> 3;
    int j = r2 & 7;
    int k = kt * 32 + (lane >> 4) * 8 + j;
    int n = nt * 16 + (lane & 15);
    float v = (k < K && n < N) ? src[(size_t)step * K * N + (size_t)k * N + n] : 0.f;
    dst[t] = f2b(v);
}

// ---------------- barrier pre-init (ws is poisoned between iterations) ----
__global__ __launch_bounds__(256) void k_pre(float* __restrict__ ws) {
    unsigned* bar = (unsigned*)(ws + BAR_OFF);
    for (int i = threadIdx.x; i < 512; i += 256) atomicExch(bar + i, 0u);
}

// ---------------- grid barrier: MONOTONIC two-level atomic tree ----------------
// 128 blocks: 8 leaves x 16 blocks. No resets -> no lost-update race.
// __syncthreads() drains each wave's vmcnt before arrival. Cross-block data is
// only read via LLC atomics/atomic-loads, so no cache fences needed.
__device__ __forceinline__ void grid_bar(unsigned* bar, unsigned gen, int bid) {
    __syncthreads();
    if (threadIdx.x == 0) {
        unsigned* leaf = bar + (bid & 7) * 32;
        unsigned* root = bar + 256;
        unsigned* rel  = bar + 288;
        bool done = false;
        unsigned a = __hip_atomic_fetch_add(leaf, 1u, __ATOMIC_RELAXED, __HIP_MEMORY_SCOPE_AGENT);
        if (a == gen * 16u + 15u) {
            unsigned r = __hip_atomic_fetch_add(root, 1u, __ATOMIC_RELAXED, __HIP_MEMORY_SCOPE_AGENT);
            if (r == gen * 8u + 7u) {
                __hip_atomic_store(rel, gen + 1u, __ATOMIC_RELAXED, __HIP_MEMORY_SCOPE_AGENT);
                done = true;
            }
        }
        if (!done) {
            while (__hip_atomic_load(rel, __ATOMIC_RELAXED, __HIP_MEMORY_SCOPE_AGENT) < gen + 1u)
                __builtin_amdgcn_s_sleep(1);
        }
        asm volatile("" ::: "memory");
    }
    __syncthreads();
}

// BN affine constants from LLC-coherent stat reads: A = relu(a*y + c)
__device__ __forceinline__ void compute_ac_coh(const float* __restrict__ si,
                                               const float* __restrict__ g,
                                               const float* __restrict__ be,
                                               float (*AC)[HP]) {
    int t = threadIdx.x;
    if (t < HP) {
        float a = 0.f, c = 0.f;
        if (t < HH) {
            float s = 0.f, q = 0.f;
            #pragma unroll
            for (int r = 0; r < 8; ++r) {
                s += ld_coh(si + r * 544 + t);
                q += ld_coh(si + r * 544 + 272 + t);
            }
            float mu  = s * (1.0f / 2048.0f);
            float var = q * (1.0f / 2048.0f) - mu * mu;
            float rs  = rsqrtf(fmaxf(var, 0.0f) + BN_EPS);
            a = g[t] * rs;
            c = be[t] - mu * a;
        }
        AC[0][t] = a;
        AC[1][t] = c;
    }
}

// ---------------- phase: [affine-relu] GEMM, NT=17, 16 rows/block ----------------
// mode 0: raw f32 global gsrc (K=KT*32); mode 2: affine(stats) on LDS lsrc.
__device__ __forceinline__ void dev_lin16(
    int bid, int mode, int KT,
    const float* __restrict__ gsrc,   // mode 0: global, stride DD
    const float* __restrict__ lsrc,   // mode 2: LDS, stride HP
    const float* __restrict__ stats_in, const float* __restrict__ g,
    const float* __restrict__ be,
    const ushort_t* __restrict__ Wq, const float* __restrict__ bias,
    float* __restrict__ ylds,         // output tile in LDS, stride HP
    float* __restrict__ stats_out,
    float* __restrict__ zero_ptr,
    ushort_t* __restrict__ As, float (*AC)[HP])
{
    const int tid  = threadIdx.x;
    const int lane = tid & 63;
    const int wv   = tid >> 6;
    const int quad = lane >> 4;
    const int l15  = lane & 15;
    const int row0 = bid * 16;

    if (zero_ptr != nullptr) {
        int z = bid * 512 + tid;
        if (z < 4352) atomicExch(zero_ptr + z, 0.0f);
    }

    if (mode == 2) { compute_ac_coh(stats_in, g, be, AC); __syncthreads(); }

    const int PAIRS = KT * 16;
    for (int idx = tid; idx < 16 * PAIRS; idx += 512) {
        int m  = idx / PAIRS;
        int kk = (idx - m * PAIRS) * 2;
        float v0, v1;
        if (mode == 2) {
            v0 = (kk < HH)   ? fmaxf(fmaf(AC[0][kk],   lsrc[m * HP + kk],   AC[1][kk]),   0.f) : 0.f;
            v1 = (kk+1 < HH) ? fmaxf(fmaf(AC[0][kk+1], lsrc[m * HP + kk+1], AC[1][kk+1]), 0.f) : 0.f;
        } else {
            v0 = gsrc[(size_t)(row0 + m) * DD + kk];
            v1 = gsrc[(size_t)(row0 + m) * DD + kk + 1];
        }
        ((unsigned int*)As)[m * (AS_STRIDE/2) + (kk >> 1)] =
            (unsigned int)f2b(v0) | ((unsigned int)f2b(v1) << 16);
    }
    __syncthreads();

    // tiles t = wv + 8*i (i<2 for all waves; i==2 only wv==0 -> t=16)
    f32x4 acc[3];
    #pragma unroll
    for (int i = 0; i < 3; ++i) acc[i] = (f32x4){0.f, 0.f, 0.f, 0.f};

    for (int kt = 0; kt < KT; ++kt) {
        short8 af = *(const short8*)(&As[l15 * AS_STRIDE + kt * 32 + quad * 8]);
        const ushort_t* wp = Wq + ((size_t)(kt * 17 + wv)) * 512 + lane * 8;
        #pragma unroll
        for (int i = 0; i < 3; ++i) {
            if (i < 2 || wv == 0) {
                short8 bf = *(const short8*)(wp + (size_t)i * 8 * 512);
                acc[i] = __builtin_amdgcn_mfma_f32_16x16x32_bf16(af, bf, acc[i], 0, 0, 0);
            }
        }
    }

    #pragma unroll
    for (int i = 0; i < 3; ++i) {
        if (i == 2 && wv != 0) continue;
        int t = wv + 8 * i;
        int col = t * 16 + l15;
        float bj = (col < HH) ? bias[col] : 0.f;
        float y0 = acc[i][0] + bj, y1 = acc[i][1] + bj;
        float y2 = acc[i][2] + bj, y3 = acc[i][3] + bj;
        ylds[(quad*4 + 0) * HP + col] = y0;
        ylds[(quad*4 + 1) * HP + col] = y1;
        ylds[(quad*4 + 2) * HP + col] = y2;
        ylds[(quad*4 + 3) * HP + col] = y3;
        float sp = y0 + y1 + y2 + y3;
        float sq = y0*y0 + y1*y1 + y2*y2 + y3*y3;
        sp += __shfl_xor(sp, 16); sp += __shfl_xor(sp, 32);
        sq += __shfl_xor(sq, 16); sq += __shfl_xor(sq, 32);
        if (quad == 0 && col < HH) {
            float* spp = stats_out + (bid & 7) * 544;
            atomicAdd(spp + col, sp);
            atomicAdd(spp + 272 + col, sq);
        }
    }
}

// ---------------- phase: P3 grad GEMM + v/xc update + P1(s+1) GEMM --------------
__device__ __forceinline__ void dev_fused16(
    int bid,
    const float* __restrict__ y2l,   // Y2 tile in LDS, stride HP
    const float* __restrict__ stats_in,
    const float* __restrict__ g2, const float* __restrict__ be2,
    const ushort_t* __restrict__ W3q, const float* __restrict__ b3,
    const float* __restrict__ law, const float* __restrict__ dWs,
    const float* __restrict__ tg, int s, int doP1,
    float* __restrict__ xcl,         // xc tile in LDS, stride DD
    float* __restrict__ vv, float* __restrict__ outv,
    const ushort_t* __restrict__ W1q, const float* __restrict__ b1n,
    float* __restrict__ y1l,         // Y1 tile in LDS, stride HP
    float* __restrict__ stats_out,
    float* __restrict__ zero_ptr,
    ushort_t* __restrict__ As, float (*AC)[HP], float* __restrict__ red)
{
    const int tid  = threadIdx.x;
    const int lane = tid & 63;
    const int wv   = tid >> 6;
    const int quad = lane >> 4;
    const int l15  = lane & 15;
    const int row0 = bid * 16;

    if (zero_ptr != nullptr) {
        int z = bid * 512 + tid;
        if (z < 4352) atomicExch(zero_ptr + z, 0.0f);
    }

    compute_ac_coh(stats_in, g2, be2, AC);
    __syncthreads();

    // stage A2 = relu(affine(Y2)): 16 rows x 288 (K padded)
    for (int idx = tid; idx < 16 * 144; idx += 512) {
        int m  = idx / 144;
        int kk = (idx - m * 144) * 2;
        float v0 = (kk < HH)   ? fmaxf(fmaf(AC[0][kk],   y2l[m * HP + kk],   AC[1][kk]),   0.f) : 0.f;
        float v1 = (kk+1 < HH) ? fmaxf(fmaf(AC[0][kk+1], y2l[m * HP + kk+1], AC[1][kk+1]), 0.f) : 0.f;
        ((unsigned int*)As)[m * (AS_STRIDE/2) + (kk >> 1)] =
            (unsigned int)f2b(v0) | ((unsigned int)f2b(v1) << 16);
    }
    __syncthreads();

    // P3 GEMM: KT=9, NT=16, tiles t = wv, wv+8
    f32x4 acc[2];
    acc[0] = (f32x4){0.f,0.f,0.f,0.f};
    acc[1] = (f32x4){0.f,0.f,0.f,0.f};
    for (int kt = 0; kt < 9; ++kt) {
        short8 af = *(const short8*)(&As[l15 * AS_STRIDE + kt * 32 + quad * 8]);
        const ushort_t* wp = W3q + ((size_t)(kt * 16 + wv)) * 512 + lane * 8;
        acc[0] = __builtin_amdgcn_mfma_f32_16x16x32_bf16(af, *(const short8*)(wp),           acc[0], 0, 0, 0);
        acc[1] = __builtin_amdgcn_mfma_f32_16x16x32_bf16(af, *(const short8*)(wp + 8 * 512), acc[1], 0, 0, 0);
    }

    // epilogue: grad, row partials
    const float h   = tg[s + 1] - tg[s];
    const float srt = SIG * sqrtf(h);
    float grad[2][4], xcv[2][4], dwv[2][4];
    float sxr[4] = {0,0,0,0}, sgr[4] = {0,0,0,0}, sgnr[4] = {0,0,0,0};
    #pragma unroll
    for (int i = 0; i < 2; ++i) {
        int col = (wv + 8*i) * 16 + l15;
        #pragma unroll
        for (int r = 0; r < 4; ++r) {
            int rl = quad * 4 + r;
            float gd = acc[i][r] + b3[col];
            float xv = xcl[rl * DD + col];
            float dw = dWs[(size_t)(row0 + rl) * DD + col];
            float d  = xv - law[col];
            grad[i][r] = gd; xcv[i][r] = xv; dwv[i][r] = dw;
            sxr[r]  = fmaf(d, d, sxr[r]);
            sgr[r]  = fmaf(gd, gd, sgr[r]);
            sgnr[r] = fmaf(gd, dw, sgnr[r]);
        }
    }
    #pragma unroll
    for (int off = 1; off < 16; off <<= 1) {
        #pragma unroll
        for (int r = 0; r < 4; ++r) {
            sxr[r]  += __shfl_xor(sxr[r],  off);
            sgr[r]  += __shfl_xor(sgr[r],  off);
            sgnr[r] += __shfl_xor(sgnr[r], off);
        }
    }
    if (l15 == 0) {
        #pragma unroll
        for (int r = 0; r < 4; ++r) {
            int rr = quad * 4 + r;
            red[(wv * 16 + rr) * 3 + 0] = sxr[r];
            red[(wv * 16 + rr) * 3 + 1] = sgr[r];
            red[(wv * 16 + rr) * 3 + 2] = sgnr[r];
        }
    }
    __syncthreads();   // red ready; all waves done reading As (P3)

    if (tid < 16) {
        float sx = 0.f, sg = 0.f, sgn = 0.f;
        #pragma unroll
        for (int w = 0; w < 8; ++w) {
            sx  += red[(w * 16 + tid) * 3 + 0];
            sg  += red[(w * 16 + tid) * 3 + 1];
            sgn += red[(w * 16 + tid) * 3 + 2];
        }
        int row = row0 + tid;
        float f  = 0.5f * (sx + sg);
        float vn = vv[row] - f * h + srt * sgn;
        vv[row] = vn;
        if (s == SS - 1) outv[row] = vn;
    }

    // xc update (LDS) + stage new A1 into As (bf16)
    #pragma unroll
    for (int i = 0; i < 2; ++i) {
        int col = (wv + 8*i) * 16 + l15;
        #pragma unroll
        for (int r = 0; r < 4; ++r) {
            int rl = quad * 4 + r;
            float xn = xcv[i][r] - grad[i][r] * h + srt * dwv[i][r];
            xcl[rl * DD + col] = xn;
            if (doP1) As[rl * AS_STRIDE + col] = f2b(xn);
        }
    }
    if (!doP1) return;
    __syncthreads();

    // P1(s+1) GEMM: KT=8, NT=17
    f32x4 acc2[3];
    #pragma unroll
    for (int i = 0; i < 3; ++i) acc2[i] = (f32x4){0.f, 0.f, 0.f, 0.f};
    for (int kt = 0; kt < 8; ++kt) {
        short8 af = *(const short8*)(&As[l15 * AS_STRIDE + kt * 32 + quad * 8]);
        const ushort_t* wp = W1q + ((size_t)(kt * 17 + wv)) * 512 + lane * 8;
        #pragma unroll
        for (int i = 0; i < 3; ++i) {
            if (i < 2 || wv == 0) {
                short8 bf = *(const short8*)(wp + (size_t)i * 8 * 512);
                acc2[i] = __builtin_amdgcn_mfma_f32_16x16x32_bf16(af, bf, acc2[i], 0, 0, 0);
            }
        }
    }
    #pragma unroll
    for (int i = 0; i < 3; ++i) {
        if (i == 2 && wv != 0) continue;
        int t = wv + 8 * i;
        int col = t * 16 + l15;
        float bj = (col < HH) ? b1n[col] : 0.f;
        float y0 = acc2[i][0] + bj, y1 = acc2[i][1] + bj;
        float y2 = acc2[i][2] + bj, y3 = acc2[i][3] + bj;
        y1l[(quad*4 + 0) * HP + col] = y0;
        y1l[(quad*4 + 1) * HP + col] = y1;
        y1l[(quad*4 + 2) * HP + col] = y2;
        y1l[(quad*4 + 3) * HP + col] = y3;
        float sp = y0 + y1 + y2 + y3;
        float sq = y0*y0 + y1*y1 + y2*y2 + y3*y3;
        sp += __shfl_xor(sp, 16); sp += __shfl_xor(sp, 32);
        sq += __shfl_xor(sq, 16); sq += __shfl_xor(sq, 32);
        if (quad == 0 && col < HH) {
            float* spp = stats_out + (bid & 7) * 544;
            atomicAdd(spp + col, sp);
            atomicAdd(spp + 272 + col, sq);
        }
    }
}

// ---------------- v0 layer 3 (N=1), 16 rows/block, 32 lanes per row ------------
__device__ __forceinline__ void dev_v0l3_16(
    int bid, const float* __restrict__ y2l, const float* __restrict__ stats_in,
    const float* __restrict__ gv, const float* __restrict__ bev,
    const float* __restrict__ wv3, const float* __restrict__ bv3,
    float* __restrict__ vout, float* __restrict__ sv,
    float (*AC)[HP], float* __restrict__ xtra)
{
    const int tid = threadIdx.x;
    compute_ac_coh(stats_in, gv, bev, AC);
    __syncthreads();

    const int r   = tid >> 5;           // 0..15 (32 lanes per row)
    const int ks  = tid & 31;
    int k0 = ks * 9, k1 = k0 + 9;
    if (k1 > HH) k1 = HH;
    float acc = 0.0f;
    for (int k = k0; k < k1; ++k) {
        float y  = y2l[r * HP + k];
        float a2 = fmaxf(fmaf(AC[0][k], y, AC[1][k]), 0.0f);
        acc = fmaf(a2, wv3[k], acc);
    }
    #pragma unroll
    for (int off = 1; off < 32; off <<= 1) acc += __shfl_xor(acc, off);
    if (ks == 0) {
        float y = acc + bv3[0];
        vout[bid * 16 + r] = y;
        xtra[r] = y;
        xtra[16 + r] = y * y;
    }
    __syncthreads();
    if (tid == 0) {
        float s = 0.f, q = 0.f;
        #pragma unroll
        for (int i = 0; i < 16; ++i) { s += xtra[i]; q += xtra[16 + i]; }
        atomicAdd(sv, s);
        atomicAdd(sv + 1, q);
    }
}

__device__ __forceinline__ void dev_v0fin16(int bid, float* __restrict__ v,
                                            const float* __restrict__ sv,
                                            const float* __restrict__ gv3,
                                            const float* __restrict__ bev3) {
    if (threadIdx.x < 16) {
        float s0 = ld_coh(sv);
        float s1 = ld_coh(sv + 1);
        float mu  = s0 * (1.0f / 2048.0f);
        float var = s1 * (1.0f / 2048.0f) - mu * mu;
        float rs  = rsqrtf(fmaxf(var, 0.0f) + BN_EPS);
        int row = bid * 16 + threadIdx.x;
        float y = v[row];
        v[row] = fmaxf(gv3[0] * (y - mu) * rs + bev3[0], 0.0f);
    }
}

// ---------------- the persistent kernel ----------------
__global__ __launch_bounds__(512) void k_persist(
    const float* __restrict__ x, const float* __restrict__ dW,
    const float* __restrict__ law, const float* __restrict__ tg,
    const float* __restrict__ b1, const float* __restrict__ g1, const float* __restrict__ be1,
    const float* __restrict__ b2, const float* __restrict__ g2, const float* __restrict__ be2,
    const float* __restrict__ b3,
    const float* __restrict__ bv1, const float* __restrict__ gv1, const float* __restrict__ bev1,
    const float* __restrict__ bv2, const float* __restrict__ gv2, const float* __restrict__ bev2,
    const float* __restrict__ Wv3, const float* __restrict__ bv3,
    const float* __restrict__ gv3, const float* __restrict__ bev3,
    float* __restrict__ ws, float* __restrict__ out)
{
    __shared__ ushort_t As[16 * AS_STRIDE];   // 9472 B
    __shared__ float AC[2][HP];               // 2176 B
    __shared__ float Y1s[16 * HP];            // 17408 B
    __shared__ float Y2s[16 * HP];            // 17408 B
    __shared__ float XCs[16 * DD];            // 16384 B
    __shared__ float XTRA[384];               // 1536 B  (red[8][16][3] / v0l3)

    const int bid = blockIdx.x;
    const int tid = threadIdx.x;

    float* V   = ws + V_OFF;
    float* S1  = ws + S1_OFF;
    float* S2  = ws + S2_OFF;
    float* S1v = ws + S1V_OFF;
    float* S2v = ws + S2V_OFF;
    float* SV  = ws + SV_OFF;
    ushort_t* WQ = (ushort_t*)(ws + WQ_OFF);
    ushort_t* W1q  = WQ + W1Q_OFF;
    ushort_t* W2q  = WQ + W2Q_OFF;
    ushort_t* W3q  = WQ + W3Q_OFF;
    ushort_t* Wv1q = WQ + WV1Q_OFF;
    ushort_t* Wv2q = WQ + WV2Q_OFF;
    unsigned* bar  = (unsigned*)(ws + BAR_OFF);

    unsigned gen = 0;
    const int sl = (bid >> 3) & 15;   // weight-prefetch slice (16 per XCD-group)

    // ph0: xc(LDS) = x rows; zero stat buffers (LLC RMW).
    for (int i = tid; i < 16 * DD; i += 512)
        XCs[i] = x[(size_t)bid * 16 * DD + i];
    {
        int z = bid * 512 + tid;
        if (z < 26128) atomicExch(S1 + z, 0.0f);
    }
    grid_bar(bar, gen, bid); gen++;

    // ph1: v0 layer 1 (x @ Wv1) -> Y1s, stats -> S1v
    dev_lin16(bid, 0, 8, x, nullptr, nullptr, nullptr, nullptr,
              Wv1q, bv1, Y1s, S1v, nullptr, As, AC);
    grid_bar(bar, gen, bid); gen++;

    // ph2: v0 layer 2 (relu(bn(Y1)) @ Wv2) -> Y2s, stats -> S2v
    dev_lin16(bid, 2, 9, nullptr, Y1s, S1v, gv1, bev1,
              Wv2q, bv2, Y2s, S2v, nullptr, As, AC);
    grid_bar(bar, gen, bid); gen++;

    // ph3: v0 layer 3 (N=1) -> V, SV
    dev_v0l3_16(bid, Y2s, S2v, gv2, bev2, Wv3, bv3, V, SV, AC, XTRA);
    grid_bar(bar, gen, bid); gen++;

    // ph4: v0 final BN+relu on V + P1(0): x @ W1[0] -> Y1s, stats -> S1[0]
    dev_v0fin16(bid, V, SV, gv3, bev3);
    dev_lin16(bid, 0, 8, x, nullptr, nullptr, nullptr, nullptr,
              W1q, b1, Y1s, S1, nullptr, As, AC);
    // prefetch W2(0) slice for P2(0) while waiting
    prefetch16((const char*)W2q + sl * 9792, 612, tid);
    grid_bar(bar, gen, bid); gen++;

    // main loop: 2 phases (2 barriers) per step
    for (int s = 0; s < SS; ++s) {
        int p = s & 1;
        // P2: relu(bn(Y1)) @ W2[s] -> Y2s, stats -> S2[p]; zero S1[1-p]
        dev_lin16(bid, 2, 9, nullptr, Y1s, S1 + p * 4352,
                  g1 + s * HH, be1 + s * HH,
                  W2q + (size_t)s * W2S, b2 + s * HH,
                  Y2s, S2 + p * 4352, S1 + (1 - p) * 4352, As, AC);
        // prefetch F(s) inputs while waiting: private dW rows, W3(s), W1(s+1)
        prefetch16(dW + (size_t)s * BATCH * DD + (size_t)bid * 16 * DD, 1024, tid);
        prefetch16((const char*)(W3q + (size_t)s * W3S) + sl * 9216, 576, tid);
        if (s + 1 < SS)
            prefetch16((const char*)(W1q + (size_t)(s + 1) * W1S) + sl * 8704, 544, tid);
        grid_bar(bar, gen, bid); gen++;

        // F: P3 grad + v/xc update + P1(s+1) -> Y1s, stats -> S1[1-p]; zero S2[1-p]
        int sn = (s + 1 < SS) ? s + 1 : 0;   // dummy valid ptrs when doP1==0
        dev_fused16(bid, Y2s, S2 + p * 4352,
                    g2 + s * HH, be2 + s * HH,
                    W3q + (size_t)s * W3S, b3 + s * DD,
                    law + s * DD, dW + (size_t)s * BATCH * DD,
                    tg, s, (s < SS - 1) ? 1 : 0,
                    XCs, V, out,
                    W1q + (size_t)sn * W1S, b1 + sn * HH,
                    Y1s, S1 + ((s + 1) & 1) * 4352,
                    S2 + (1 - p) * 4352, As, AC, XTRA);
        // prefetch W2(s+1) slice for next P2 while waiting
        if (s + 1 < SS)
            prefetch16((const char*)(W2q + (size_t)(s + 1) * W2S) + sl * 9792, 612, tid);
        grid_bar(bar, gen, bid); gen++;
    }
}

extern "C" void kernel_launch(void* const* d_in, const int* in_sizes, int n_in,
                              void* d_out, int out_size, void* d_ws, size_t ws_size,
                              hipStream_t stream)
{
    (void)in_sizes; (void)n_in; (void)out_size; (void)ws_size;
    const float* x    = (const float*)d_in[0];
    const float* dW   = (const float*)d_in[1];
    const float* law  = (const float*)d_in[2];
    const float* tg   = (const float*)d_in[3];
    const float* W1   = (const float*)d_in[4];
    const float* b1   = (const float*)d_in[5];
    const float* g1   = (const float*)d_in[6];
    const float* be1  = (const float*)d_in[7];
    const float* W2   = (const float*)d_in[8];
    const float* b2   = (const float*)d_in[9];
    const float* g2   = (const float*)d_in[10];
    const float* be2  = (const float*)d_in[11];
    const float* W3   = (const float*)d_in[12];
    const float* b3   = (const float*)d_in[13];
    const float* Wv1  = (const float*)d_in[14];
    const float* bv1  = (const float*)d_in[15];
    const float* gv1  = (const float*)d_in[16];
    const float* bev1 = (const float*)d_in[17];
    const float* Wv2  = (const float*)d_in[18];
    const float* bv2  = (const float*)d_in[19];
    const float* gv2  = (const float*)d_in[20];
    const float* bev2 = (const float*)d_in[21];
    const float* Wv3  = (const float*)d_in[22];
    const float* bv3  = (const float*)d_in[23];
    const float* gv3  = (const float*)d_in[24];
    const float* bev3 = (const float*)d_in[25];

    float* ws = (float*)d_ws;
    ushort_t* WQ = (ushort_t*)(ws + WQ_OFF);
    ushort_t* W1q  = WQ + W1Q_OFF;
    ushort_t* W2q  = WQ + W2Q_OFF;
    ushort_t* W3q  = WQ + W3Q_OFF;
    ushort_t* Wv1q = WQ + WV1Q_OFF;
    ushort_t* Wv2q = WQ + WV2Q_OFF;
    float* out = (float*)d_out;

    k_pre<<<1, 256, 0, stream>>>(ws);
    k_conv<<<13600, 256, 0, stream>>>(W1,  W1q,  DD, HH, 8, 17, (long)SS * W1S);
    k_conv<<<15300, 256, 0, stream>>>(W2,  W2q,  HH, HH, 9, 17, (long)SS * W2S);
    k_conv<<<14400, 256, 0, stream>>>(W3,  W3q,  HH, DD, 9, 16, (long)SS * W3S);
    k_conv<<<272,   256, 0, stream>>>(Wv1, Wv1q, DD, HH, 8, 17, (long)W1S);
    k_conv<<<306,   256, 0, stream>>>(Wv2, Wv2q, HH, HH, 9, 17, (long)W2S);

    k_persist<<<128, 512, 0, stream>>>(
        x, dW, law, tg,
        b1, g1, be1, b2, g2, be2, b3,
        bv1, gv1, bev1, bv2, gv2, bev2,
        Wv3, bv3, gv3, bev3,
        ws, out);
}